// Round 2
// baseline (1055.779 us; speedup 1.0000x reference)
//
#include <hip/hip_runtime.h>
#include <math.h>

// Problem constants
#define NB  262144   // batch
#define SD  128      // STATE_DIM
#define HID 256      // HIDDEN
#define AD  8        // ACTION_DIM
#define RT  16       // rows per block

// d_ws layout (in floats): transposed weights + biases
#define W1T_OFF 0                       // [SD][HID]   W1T[k*HID+j] = W1[j*SD+k]
#define W2T_OFF (SD*HID)                // [HID][HID]  32768
#define W3T_OFF (W2T_OFF + HID*HID)     // [HID][16]   98304
#define B1_OFF  (W3T_OFF + HID*2*AD)    // 102400
#define B2_OFF  (B1_OFF + HID)          // 102656
#define B3_OFF  (B2_OFF + HID)          // 102912
#define WS_FLOATS (B3_OFF + 2*AD)       // 102928 floats = 411,712 bytes

__global__ __launch_bounds__(256) void prep_weights(
    const float* __restrict__ W1, const float* __restrict__ b1,
    const float* __restrict__ W2, const float* __restrict__ b2,
    const float* __restrict__ W3, const float* __restrict__ b3,
    float* __restrict__ ws) {
  int stride = gridDim.x * blockDim.x;
  for (int i = blockIdx.x * blockDim.x + threadIdx.x; i < WS_FLOATS; i += stride) {
    float v;
    if (i < W2T_OFF) {                       // W1T: k = i/256, j = i%256
      int k = i >> 8, j = i & 255;
      v = W1[j * SD + k];
    } else if (i < W3T_OFF) {                // W2T
      int t = i - W2T_OFF;
      int k = t >> 8, j = t & 255;
      v = W2[j * HID + k];
    } else if (i < B1_OFF) {                 // W3T: k = t/16, j = t%16
      int t = i - W3T_OFF;
      int k = t >> 4, j = t & 15;
      v = W3[j * HID + k];
    } else if (i < B2_OFF) {
      v = b1[i - B1_OFF];
    } else if (i < B3_OFF) {
      v = b2[i - B2_OFF];
    } else {
      v = b3[i - B3_OFF];
    }
    ws[i] = v;
  }
}

// Bit-exact replication of the numpy float32 pipeline:
//   sgemm: single fp32 accumulator per output, k ascending, fmaf (RTNE) — matches
//   OpenBLAS microkernel (vfmadd, beta=0, no K-split at K<=256).
//   bias: separate fp32 add. relu: max. epilogue: separately-rounded mul/add,
//   expf realized as (float)exp(double) (correctly rounded near the z~0 boundary),
//   IEEE fp32 division, act*8 (exact) + 1 (rounded), truncate.
__global__ __launch_bounds__(256) void actor_fused(
    const float* __restrict__ state, const float* __restrict__ eps,
    const float* __restrict__ ws, int* __restrict__ out) {
  __shared__ float s_x[RT][SD];     // 8 KB
  __shared__ float s_h1[RT][HID];   // 16 KB
  __shared__ float s_h2[RT][HID];   // 16 KB

  const float4* __restrict__ W1T4 = (const float4*)(ws + W1T_OFF);  // [SD][64]
  const float4* __restrict__ W2T4 = (const float4*)(ws + W2T_OFF);  // [HID][64]
  const float*  __restrict__ W3T  = ws + W3T_OFF;                   // [HID][16]

  const int tid = threadIdx.x;
  const long rowbase = (long)blockIdx.x * RT;

  // ---- stage state tile -> LDS (coalesced float4)
  {
    const float4* st4 = (const float4*)(state + rowbase * SD);
    float4* sx4 = (float4*)&s_x[0][0];
    #pragma unroll
    for (int i = 0; i < (RT * SD / 4) / 256; ++i) {   // 2 iters
      int idx = tid + i * 256;
      sx4[idx] = st4[idx];
    }
  }
  __syncthreads();

  const int rg = tid >> 6;    // wave id: rows r0..r0+3
  const int cg = tid & 63;    // lane: cols 4*cg..4*cg+3 (float4-contiguous)
  const int r0 = rg * 4;

  // ---- layer 1: h1 = relu(x @ W1^T + b1), K = 128
  {
    float acc[4][4];
    #pragma unroll
    for (int r = 0; r < 4; ++r)
      #pragma unroll
      for (int c = 0; c < 4; ++c) acc[r][c] = 0.0f;

    for (int k = 0; k < SD; ++k) {
      float x[4];
      #pragma unroll
      for (int r = 0; r < 4; ++r) x[r] = s_x[r0 + r][k];   // wave-uniform broadcast
      float4 w = W1T4[k * 64 + cg];                        // coalesced 16B/lane
      #pragma unroll
      for (int r = 0; r < 4; ++r) {
        acc[r][0] = fmaf(x[r], w.x, acc[r][0]);
        acc[r][1] = fmaf(x[r], w.y, acc[r][1]);
        acc[r][2] = fmaf(x[r], w.z, acc[r][2]);
        acc[r][3] = fmaf(x[r], w.w, acc[r][3]);
      }
    }
    float4 bb = ((const float4*)(ws + B1_OFF))[cg];
    #pragma unroll
    for (int r = 0; r < 4; ++r) {
      float4 v;
      v.x = acc[r][0] + bb.x; v.y = acc[r][1] + bb.y;
      v.z = acc[r][2] + bb.z; v.w = acc[r][3] + bb.w;
      v.x = v.x > 0.0f ? v.x : 0.0f;
      v.y = v.y > 0.0f ? v.y : 0.0f;
      v.z = v.z > 0.0f ? v.z : 0.0f;
      v.w = v.w > 0.0f ? v.w : 0.0f;
      ((float4*)&s_h1[r0 + r][0])[cg] = v;
    }
  }
  __syncthreads();

  // ---- layer 2: h2 = relu(h1 @ W2^T + b2), K = 256
  {
    float acc[4][4];
    #pragma unroll
    for (int r = 0; r < 4; ++r)
      #pragma unroll
      for (int c = 0; c < 4; ++c) acc[r][c] = 0.0f;

    for (int k = 0; k < HID; ++k) {
      float x[4];
      #pragma unroll
      for (int r = 0; r < 4; ++r) x[r] = s_h1[r0 + r][k];
      float4 w = W2T4[k * 64 + cg];
      #pragma unroll
      for (int r = 0; r < 4; ++r) {
        acc[r][0] = fmaf(x[r], w.x, acc[r][0]);
        acc[r][1] = fmaf(x[r], w.y, acc[r][1]);
        acc[r][2] = fmaf(x[r], w.z, acc[r][2]);
        acc[r][3] = fmaf(x[r], w.w, acc[r][3]);
      }
    }
    float4 bb = ((const float4*)(ws + B2_OFF))[cg];
    #pragma unroll
    for (int r = 0; r < 4; ++r) {
      float4 v;
      v.x = acc[r][0] + bb.x; v.y = acc[r][1] + bb.y;
      v.z = acc[r][2] + bb.z; v.w = acc[r][3] + bb.w;
      v.x = v.x > 0.0f ? v.x : 0.0f;
      v.y = v.y > 0.0f ? v.y : 0.0f;
      v.z = v.z > 0.0f ? v.z : 0.0f;
      v.w = v.w > 0.0f ? v.w : 0.0f;
      ((float4*)&s_h2[r0 + r][0])[cg] = v;
    }
  }
  __syncthreads();

  // ---- layer 3 (K=256, N=16) + epilogue
  {
    const int r3 = tid >> 4;   // 0..15
    const int c3 = tid & 15;   // 0..15
    float acc = 0.0f;
    for (int k = 0; k < HID; ++k)
      acc = fmaf(s_h2[r3][k], W3T[k * (2 * AD) + c3], acc);
    float n = acc + ws[B3_OFF + c3];

    // pair (u, s): lane xor 8 swaps col <-> col+8 within the same row
    float partner = __shfl_xor(n, 8, 64);
    if (c3 < AD) {
      long grow = rowbase + r3;
      float sa = fabsf(partner);
      float ev = eps[grow * AD + c3];
      float t  = __fmul_rn(sa, ev);        // separately-rounded mul (no contract)
      float z  = __fadd_rn(n, t);          // separately-rounded add
      float e  = (float)exp(-(double)z);   // == correctly-rounded expf near boundary
      float d  = __fadd_rn(1.0f, e);
      float act = 1.0f / d;                // IEEE fp32 division
      float q  = act * 8.0f;               // exact (power of 2)
      float w  = __fadd_rn(q, 1.0f);
      out[grow * AD + c3] = (int)w;        // truncation toward zero, as astype(int32)
    }
  }
}

extern "C" void kernel_launch(void* const* d_in, const int* in_sizes, int n_in,
                              void* d_out, int out_size, void* d_ws, size_t ws_size,
                              hipStream_t stream) {
  const float* state = (const float*)d_in[0];
  const float* W1    = (const float*)d_in[1];
  const float* b1    = (const float*)d_in[2];
  const float* W2    = (const float*)d_in[3];
  const float* b2    = (const float*)d_in[4];
  const float* W3    = (const float*)d_in[5];
  const float* b3    = (const float*)d_in[6];
  const float* eps   = (const float*)d_in[7];
  int*   out = (int*)d_out;
  float* ws  = (float*)d_ws;   // 411,712 bytes; rebuilt every launch

  hipLaunchKernelGGL(prep_weights, dim3(128), dim3(256), 0, stream,
                     W1, b1, W2, b2, W3, b3, ws);
  hipLaunchKernelGGL(actor_fused, dim3(NB / RT), dim3(256), 0, stream,
                     state, eps, ws, out);
}

// Round 3
// 994.719 us; speedup vs baseline: 1.0614x; 1.0614x over previous
//
#include <hip/hip_runtime.h>
#include <math.h>

// Problem constants
#define NB  262144   // batch
#define SD  128      // STATE_DIM
#define HID 256      // HIDDEN
#define AD  8        // ACTION_DIM

typedef float v2f __attribute__((ext_vector_type(2)));

// d_ws layout (floats)
#define W1T_OFF 0                       // [SD][HID]   W1T[k*HID+j] = W1[j*SD+k]
#define W2T_OFF (SD*HID)                // [HID][HID]  32768
#define W3P_OFF (W2T_OFF + HID*HID)     // [HID][AD] float2 pairs (u,s): 98304, 4096 floats
#define B1_OFF  (W3P_OFF + HID*2*AD)    // 102400
#define B2_OFF  (B1_OFF + HID)          // 102656
#define B3P_OFF (B2_OFF + HID)          // 102912, [AD] float2 pairs
#define WS_FLOATS (B3P_OFF + 2*AD)      // 102928 floats = 411,712 bytes

__global__ __launch_bounds__(256) void prep_weights(
    const float* __restrict__ W1, const float* __restrict__ b1,
    const float* __restrict__ W2, const float* __restrict__ b2,
    const float* __restrict__ W3, const float* __restrict__ b3,
    float* __restrict__ ws) {
  int stride = gridDim.x * blockDim.x;
  for (int i = blockIdx.x * blockDim.x + threadIdx.x; i < WS_FLOATS; i += stride) {
    float v;
    if (i < W2T_OFF) {                       // W1T
      int k = i >> 8, j = i & 255;
      v = W1[j * SD + k];
    } else if (i < W3P_OFF) {                // W2T
      int t = i - W2T_OFF;
      int k = t >> 8, j = t & 255;
      v = W2[j * HID + k];
    } else if (i < B1_OFF) {                 // W3P[k][a] = (W3[a][k], W3[a+8][k])
      int t = i - W3P_OFF;
      int k = t >> 4, a = (t >> 1) & 7, h = t & 1;
      v = W3[(a + 8 * h) * HID + k];
    } else if (i < B2_OFF) {
      v = b1[i - B1_OFF];
    } else if (i < B3P_OFF) {
      v = b2[i - B2_OFF];
    } else {                                 // B3P[a] = (b3[a], b3[a+8])
      int t = i - B3P_OFF;
      v = b3[(t >> 1) + 8 * (t & 1)];
    }
    ws[i] = v;
  }
}

// readlane: wave-uniform broadcast of another lane's register -> SGPR
__device__ __forceinline__ float rdl(float v, int lane) {
  return __int_as_float(__builtin_amdgcn_readlane(__float_as_int(v), lane));
}

// Packed fp32 FMA, broadcast scalar in SGPR pair. Bit-exact IEEE f32 fma per
// half (identical rounding to v_fma_f32); packing is across output columns,
// never across k, so the per-output serial accumulation chain is preserved.
__device__ __forceinline__ v2f pkfma(v2f a_sgpr, v2f b, v2f c) {
  asm("v_pk_fma_f32 %0, %1, %2, %0" : "+v"(c) : "s"(a_sgpr), "v"(b));
  return c;
}

// Register-resident fused MLP. 4 waves/block, 8 rows/wave (32 rows/block).
// Layers 1-2: activations in VGPRs; wave-uniform x via v_readlane -> SGPR pair
// -> v_pk_fma_f32 scalar operand. No LDS, no barriers in the main loops.
// Layer 3: h2 round-trips through wave-private LDS rows (stride 264 floats:
// 16B-aligned for b128 writes, bank-advance 8/row -> 2-way broadcast reads, free).
__global__ __launch_bounds__(256, 4) void actor_fused(
    const float* __restrict__ state, const float* __restrict__ eps,
    const float* __restrict__ ws, int* __restrict__ out) {
  __shared__ float s_h2[32][264];   // 33,792 B -> 4 blocks/CU

  const int tid  = threadIdx.x;
  const int lane = tid & 63;
  const int wv   = tid >> 6;
  const long wrow = (long)blockIdx.x * 32 + wv * 8;   // this wave's first row

  const float4* __restrict__ W1T4 = (const float4*)(ws + W1T_OFF);  // [SD][64]
  const float4* __restrict__ W2T4 = (const float4*)(ws + W2T_OFF);  // [HID][64]
  const v2f*    __restrict__ W3P  = (const v2f*)(ws + W3P_OFF);     // [HID][8]

  // ---- stage x into registers: 8 rows x 2 floats/lane (coalesced dwordx2)
  v2f xr[8];
  #pragma unroll
  for (int r = 0; r < 8; ++r)
    xr[r] = *(const v2f*)(state + (wrow + r) * SD + 2 * lane);

  // ---- layer 1: h1 = relu(x @ W1^T + b1), K = 128
  v2f acc[8][2];
  #pragma unroll
  for (int r = 0; r < 8; ++r) { acc[r][0] = (v2f)0.0f; acc[r][1] = (v2f)0.0f; }

  #pragma unroll 2
  for (int k0 = 0; k0 < SD; k0 += 4) {
    float4 w[4];
    #pragma unroll
    for (int j = 0; j < 4; ++j) w[j] = W1T4[(k0 + j) * 64 + lane];
    #pragma unroll
    for (int j = 0; j < 4; ++j) {
      const int src = (k0 >> 1) + (j >> 1);       // uniform source lane
      v2f wlo = {w[j].x, w[j].y};
      v2f whi = {w[j].z, w[j].w};
      #pragma unroll
      for (int r = 0; r < 8; ++r) {
        float x = rdl((j & 1) ? xr[r].y : xr[r].x, src);
        v2f xs = {x, x};                          // uniform -> SGPR pair
        acc[r][0] = pkfma(xs, wlo, acc[r][0]);
        acc[r][1] = pkfma(xs, whi, acc[r][1]);
      }
    }
  }

  // bias + relu -> h1 regs (lane holds cols 4*lane..4*lane+3 of its 8 rows)
  float h1[8][4];
  {
    float4 bb = ((const float4*)(ws + B1_OFF))[lane];
    #pragma unroll
    for (int r = 0; r < 8; ++r) {
      float v0 = acc[r][0].x + bb.x, v1 = acc[r][0].y + bb.y;
      float v2 = acc[r][1].x + bb.z, v3 = acc[r][1].y + bb.w;
      h1[r][0] = v0 > 0.0f ? v0 : 0.0f;
      h1[r][1] = v1 > 0.0f ? v1 : 0.0f;
      h1[r][2] = v2 > 0.0f ? v2 : 0.0f;
      h1[r][3] = v3 > 0.0f ? v3 : 0.0f;
    }
  }

  // ---- layer 2: h2 = relu(h1 @ W2^T + b2), K = 256
  #pragma unroll
  for (int r = 0; r < 8; ++r) { acc[r][0] = (v2f)0.0f; acc[r][1] = (v2f)0.0f; }

  #pragma unroll 2
  for (int k0 = 0; k0 < HID; k0 += 4) {
    float4 w[4];
    #pragma unroll
    for (int j = 0; j < 4; ++j) w[j] = W2T4[(k0 + j) * 64 + lane];
    const int src = k0 >> 2;                      // h1[r][k0+j] lives in lane k0/4, reg j
    #pragma unroll
    for (int j = 0; j < 4; ++j) {
      v2f wlo = {w[j].x, w[j].y};
      v2f whi = {w[j].z, w[j].w};
      #pragma unroll
      for (int r = 0; r < 8; ++r) {
        float x = rdl(h1[r][j], src);
        v2f xs = {x, x};
        acc[r][0] = pkfma(xs, wlo, acc[r][0]);
        acc[r][1] = pkfma(xs, whi, acc[r][1]);
      }
    }
  }

  // bias + relu -> wave-private LDS rows (no barrier needed)
  {
    float4 bb = ((const float4*)(ws + B2_OFF))[lane];
    #pragma unroll
    for (int r = 0; r < 8; ++r) {
      float4 hv;
      hv.x = acc[r][0].x + bb.x; hv.y = acc[r][0].y + bb.y;
      hv.z = acc[r][1].x + bb.z; hv.w = acc[r][1].y + bb.w;
      hv.x = hv.x > 0.0f ? hv.x : 0.0f;
      hv.y = hv.y > 0.0f ? hv.y : 0.0f;
      hv.z = hv.z > 0.0f ? hv.z : 0.0f;
      hv.w = hv.w > 0.0f ? hv.w : 0.0f;
      *(float4*)&s_h2[wv * 8 + r][4 * lane] = hv;
    }
  }

  // ---- layer 3 (K=256, N=16) + epilogue. Lane -> (row = lane>>3, action = lane&7),
  // computes both u and s chains (each serial k-ascending, matching sgemm).
  {
    const int r3 = lane >> 3;
    const int a  = lane & 7;
    const float* __restrict__ h2row = &s_h2[wv * 8 + r3][0];
    float accu = 0.0f, accs = 0.0f;
    #pragma unroll 2
    for (int k0 = 0; k0 < HID; k0 += 4) {
      v2f ha = *(const v2f*)(h2row + k0);         // ds_read_b64, broadcast to 8 lanes
      v2f hb = *(const v2f*)(h2row + k0 + 2);
      v2f wp0 = W3P[(k0 + 0) * 8 + a];
      v2f wp1 = W3P[(k0 + 1) * 8 + a];
      v2f wp2 = W3P[(k0 + 2) * 8 + a];
      v2f wp3 = W3P[(k0 + 3) * 8 + a];
      accu = fmaf(ha.x, wp0.x, accu); accs = fmaf(ha.x, wp0.y, accs);
      accu = fmaf(ha.y, wp1.x, accu); accs = fmaf(ha.y, wp1.y, accs);
      accu = fmaf(hb.x, wp2.x, accu); accs = fmaf(hb.x, wp2.y, accs);
      accu = fmaf(hb.y, wp3.x, accu); accs = fmaf(hb.y, wp3.y, accs);
    }
    v2f b3p = ((const v2f*)(ws + B3P_OFF))[a];
    float nu = accu + b3p.x;
    float ns = accs + b3p.y;

    long grow = wrow + r3;
    float sa = fabsf(ns);
    float ev = eps[grow * AD + a];                // coalesced: base + lane
    float t  = __fmul_rn(sa, ev);                 // separately-rounded mul
    float z  = __fadd_rn(nu, t);                  // separately-rounded add
    float e  = (float)exp(-(double)z);            // correctly-rounded expf near boundary
    float d  = __fadd_rn(1.0f, e);
    float act = 1.0f / d;
    float q  = act * 8.0f;                        // exact
    float wq = __fadd_rn(q, 1.0f);
    out[grow * AD + a] = (int)wq;                 // truncation, as astype(int32)
  }
}

extern "C" void kernel_launch(void* const* d_in, const int* in_sizes, int n_in,
                              void* d_out, int out_size, void* d_ws, size_t ws_size,
                              hipStream_t stream) {
  const float* state = (const float*)d_in[0];
  const float* W1    = (const float*)d_in[1];
  const float* b1    = (const float*)d_in[2];
  const float* W2    = (const float*)d_in[3];
  const float* b2    = (const float*)d_in[4];
  const float* W3    = (const float*)d_in[5];
  const float* b3    = (const float*)d_in[6];
  const float* eps   = (const float*)d_in[7];
  int*   out = (int*)d_out;
  float* ws  = (float*)d_ws;   // 411,712 bytes; rebuilt every launch

  hipLaunchKernelGGL(prep_weights, dim3(128), dim3(256), 0, stream,
                     W1, b1, W2, b2, W3, b3, ws);
  hipLaunchKernelGGL(actor_fused, dim3(NB / 32), dim3(256), 0, stream,
                     state, eps, ws, out);
}

// Round 4
// 929.623 us; speedup vs baseline: 1.1357x; 1.0700x over previous
//
#include <hip/hip_runtime.h>
#include <math.h>

// Problem constants
#define NB  262144   // batch
#define SD  128      // STATE_DIM
#define HID 256      // HIDDEN
#define AD  8        // ACTION_DIM

typedef float v2f __attribute__((ext_vector_type(2)));

// d_ws layout (floats)
#define W1T_OFF 0                       // [SD][HID]   W1T[k*HID+j] = W1[j*SD+k]
#define W2T_OFF (SD*HID)                // [HID][HID]  32768
#define W3P_OFF (W2T_OFF + HID*HID)     // [HID][AD] float2 pairs (u,s): 98304, 4096 floats
#define B1_OFF  (W3P_OFF + HID*2*AD)    // 102400
#define B2_OFF  (B1_OFF + HID)          // 102656
#define B3P_OFF (B2_OFF + HID)          // 102912, [AD] float2 pairs
#define WS_FLOATS (B3P_OFF + 2*AD)      // 102928 floats = 411,712 bytes

__global__ __launch_bounds__(256) void prep_weights(
    const float* __restrict__ W1, const float* __restrict__ b1,
    const float* __restrict__ W2, const float* __restrict__ b2,
    const float* __restrict__ W3, const float* __restrict__ b3,
    float* __restrict__ ws) {
  int stride = gridDim.x * blockDim.x;
  for (int i = blockIdx.x * blockDim.x + threadIdx.x; i < WS_FLOATS; i += stride) {
    float v;
    if (i < W2T_OFF) {                       // W1T
      int k = i >> 8, j = i & 255;
      v = W1[j * SD + k];
    } else if (i < W3P_OFF) {                // W2T
      int t = i - W2T_OFF;
      int k = t >> 8, j = t & 255;
      v = W2[j * HID + k];
    } else if (i < B1_OFF) {                 // W3P[k][a] = (W3[a][k], W3[a+8][k])
      int t = i - W3P_OFF;
      int k = t >> 4, a = (t >> 1) & 7, h = t & 1;
      v = W3[(a + 8 * h) * HID + k];
    } else if (i < B2_OFF) {
      v = b1[i - B1_OFF];
    } else if (i < B3P_OFF) {
      v = b2[i - B2_OFF];
    } else {                                 // B3P[a] = (b3[a], b3[a+8])
      int t = i - B3P_OFF;
      v = b3[(t >> 1) + 8 * (t & 1)];
    }
    ws[i] = v;
  }
}

// readlane: wave-uniform broadcast -> SGPR. The result is uniform in the
// compiler's divergence analysis, so fmaf(x, w, acc) emits
// v_fmac_f32 vdst, sgpr, vgpr (1 SGPR read per VALU op is legal) — full-rate
// fp32 FMA with zero broadcast-materialization cost.
// NOTE (R3 post-mortem): v_pk_fma_f32 measured ~half per-lane fp32 throughput
// vs v_fma_f32 on gfx950 — packed fp32 does NOT raise the 157.3 TF wall.
__device__ __forceinline__ float rdl(float v, int lane) {
  return __int_as_float(__builtin_amdgcn_readlane(__float_as_int(v), lane));
}

// Register-resident fused MLP. 4 waves/block, 8 rows/wave (32 rows/block).
// Layers 1-2: activations in VGPRs; wave-uniform x via v_readlane (SGPR) feeds
// scalar-operand v_fmac_f32. No LDS, no barriers in the main loops.
// Layer 3: h2 round-trips through wave-private LDS rows (stride 264 floats:
// 16B-aligned for b128 writes; reads are 8-lane broadcasts, conflict-free).
__global__ __launch_bounds__(256, 4) void actor_fused(
    const float* __restrict__ state, const float* __restrict__ eps,
    const float* __restrict__ ws, int* __restrict__ out) {
  __shared__ float s_h2[32][264];   // 33,792 B -> 4 blocks/CU

  const int tid  = threadIdx.x;
  const int lane = tid & 63;
  const int wv   = tid >> 6;
  const long wrow = (long)blockIdx.x * 32 + wv * 8;   // this wave's first row

  const float4* __restrict__ W1T4 = (const float4*)(ws + W1T_OFF);  // [SD][64]
  const float4* __restrict__ W2T4 = (const float4*)(ws + W2T_OFF);  // [HID][64]
  const v2f*    __restrict__ W3P  = (const v2f*)(ws + W3P_OFF);     // [HID][8]

  // ---- stage x into registers: 8 rows x 2 floats/lane (coalesced dwordx2)
  v2f xr[8];
  #pragma unroll
  for (int r = 0; r < 8; ++r)
    xr[r] = *(const v2f*)(state + (wrow + r) * SD + 2 * lane);

  // ---- layer 1: h1 = relu(x @ W1^T + b1), K = 128
  float acc[8][4];
  #pragma unroll
  for (int r = 0; r < 8; ++r)
    #pragma unroll
    for (int c = 0; c < 4; ++c) acc[r][c] = 0.0f;

  #pragma unroll 2
  for (int k0 = 0; k0 < SD; k0 += 4) {
    float4 w[4];
    #pragma unroll
    for (int j = 0; j < 4; ++j) w[j] = W1T4[(k0 + j) * 64 + lane];
    #pragma unroll
    for (int j = 0; j < 4; ++j) {
      const int src = (k0 >> 1) + (j >> 1);       // x[r][k0+j] lives in lane src
      #pragma unroll
      for (int r = 0; r < 8; ++r) {
        float x = rdl((j & 1) ? xr[r].y : xr[r].x, src);   // SGPR broadcast
        acc[r][0] = fmaf(x, w[j].x, acc[r][0]);
        acc[r][1] = fmaf(x, w[j].y, acc[r][1]);
        acc[r][2] = fmaf(x, w[j].z, acc[r][2]);
        acc[r][3] = fmaf(x, w[j].w, acc[r][3]);
      }
    }
  }

  // bias + relu -> h1 regs (lane holds cols 4*lane..4*lane+3 of its 8 rows)
  float h1[8][4];
  {
    float4 bb = ((const float4*)(ws + B1_OFF))[lane];
    #pragma unroll
    for (int r = 0; r < 8; ++r) {
      float v0 = acc[r][0] + bb.x, v1 = acc[r][1] + bb.y;
      float v2 = acc[r][2] + bb.z, v3 = acc[r][3] + bb.w;
      h1[r][0] = v0 > 0.0f ? v0 : 0.0f;
      h1[r][1] = v1 > 0.0f ? v1 : 0.0f;
      h1[r][2] = v2 > 0.0f ? v2 : 0.0f;
      h1[r][3] = v3 > 0.0f ? v3 : 0.0f;
    }
  }

  // ---- layer 2: h2 = relu(h1 @ W2^T + b2), K = 256
  #pragma unroll
  for (int r = 0; r < 8; ++r)
    #pragma unroll
    for (int c = 0; c < 4; ++c) acc[r][c] = 0.0f;

  #pragma unroll 2
  for (int k0 = 0; k0 < HID; k0 += 4) {
    float4 w[4];
    #pragma unroll
    for (int j = 0; j < 4; ++j) w[j] = W2T4[(k0 + j) * 64 + lane];
    const int src = k0 >> 2;                      // h1[r][k0+j] lives in lane k0/4, reg j
    #pragma unroll
    for (int j = 0; j < 4; ++j) {
      #pragma unroll
      for (int r = 0; r < 8; ++r) {
        float x = rdl(h1[r][j], src);             // SGPR broadcast
        acc[r][0] = fmaf(x, w[j].x, acc[r][0]);
        acc[r][1] = fmaf(x, w[j].y, acc[r][1]);
        acc[r][2] = fmaf(x, w[j].z, acc[r][2]);
        acc[r][3] = fmaf(x, w[j].w, acc[r][3]);
      }
    }
  }

  // bias + relu -> wave-private LDS rows (no barrier needed)
  {
    float4 bb = ((const float4*)(ws + B2_OFF))[lane];
    #pragma unroll
    for (int r = 0; r < 8; ++r) {
      float4 hv;
      hv.x = acc[r][0] + bb.x; hv.y = acc[r][1] + bb.y;
      hv.z = acc[r][2] + bb.z; hv.w = acc[r][3] + bb.w;
      hv.x = hv.x > 0.0f ? hv.x : 0.0f;
      hv.y = hv.y > 0.0f ? hv.y : 0.0f;
      hv.z = hv.z > 0.0f ? hv.z : 0.0f;
      hv.w = hv.w > 0.0f ? hv.w : 0.0f;
      *(float4*)&s_h2[wv * 8 + r][4 * lane] = hv;
    }
  }

  // ---- layer 3 (K=256, N=16) + epilogue. Lane -> (row = lane>>3, action = lane&7),
  // computes both u and s chains (each serial k-ascending, matching sgemm).
  {
    const int r3 = lane >> 3;
    const int a  = lane & 7;
    const float* __restrict__ h2row = &s_h2[wv * 8 + r3][0];
    float accu = 0.0f, accs = 0.0f;
    #pragma unroll 2
    for (int k0 = 0; k0 < HID; k0 += 4) {
      v2f ha = *(const v2f*)(h2row + k0);         // ds_read_b64, broadcast to 8 lanes
      v2f hb = *(const v2f*)(h2row + k0 + 2);
      v2f wp0 = W3P[(k0 + 0) * 8 + a];
      v2f wp1 = W3P[(k0 + 1) * 8 + a];
      v2f wp2 = W3P[(k0 + 2) * 8 + a];
      v2f wp3 = W3P[(k0 + 3) * 8 + a];
      accu = fmaf(ha.x, wp0.x, accu); accs = fmaf(ha.x, wp0.y, accs);
      accu = fmaf(ha.y, wp1.x, accu); accs = fmaf(ha.y, wp1.y, accs);
      accu = fmaf(hb.x, wp2.x, accu); accs = fmaf(hb.x, wp2.y, accs);
      accu = fmaf(hb.y, wp3.x, accu); accs = fmaf(hb.y, wp3.y, accs);
    }
    v2f b3p = ((const v2f*)(ws + B3P_OFF))[a];
    float nu = accu + b3p.x;
    float ns = accs + b3p.y;

    long grow = wrow + r3;
    float sa = fabsf(ns);
    float ev = eps[grow * AD + a];                // coalesced: base + lane
    float t  = __fmul_rn(sa, ev);                 // separately-rounded mul
    float z  = __fadd_rn(nu, t);                  // separately-rounded add
    float e  = (float)exp(-(double)z);            // correctly-rounded expf near boundary
    float d  = __fadd_rn(1.0f, e);
    float act = 1.0f / d;
    float q  = act * 8.0f;                        // exact
    float wq = __fadd_rn(q, 1.0f);
    out[grow * AD + a] = (int)wq;                 // truncation, as astype(int32)
  }
}

extern "C" void kernel_launch(void* const* d_in, const int* in_sizes, int n_in,
                              void* d_out, int out_size, void* d_ws, size_t ws_size,
                              hipStream_t stream) {
  const float* state = (const float*)d_in[0];
  const float* W1    = (const float*)d_in[1];
  const float* b1    = (const float*)d_in[2];
  const float* W2    = (const float*)d_in[3];
  const float* b2    = (const float*)d_in[4];
  const float* W3    = (const float*)d_in[5];
  const float* b3    = (const float*)d_in[6];
  const float* eps   = (const float*)d_in[7];
  int*   out = (int*)d_out;
  float* ws  = (float*)d_ws;   // 411,712 bytes; rebuilt every launch

  hipLaunchKernelGGL(prep_weights, dim3(128), dim3(256), 0, stream,
                     W1, b1, W2, b2, W3, b3, ws);
  hipLaunchKernelGGL(actor_fused, dim3(NB / 32), dim3(256), 0, stream,
                     state, eps, ws, out);
}

// Round 5
// 877.083 us; speedup vs baseline: 1.2037x; 1.0599x over previous
//
#include <hip/hip_runtime.h>
#include <math.h>

// Problem constants
#define NB  262144   // batch
#define SD  128      // STATE_DIM
#define HID 256      // HIDDEN
#define AD  8        // ACTION_DIM

typedef float v2f __attribute__((ext_vector_type(2)));

// d_ws layout (floats)
#define W1T_OFF 0                       // [SD][HID]   W1T[k*HID+j] = W1[j*SD+k]
#define W2T_OFF (SD*HID)                // [HID][HID]  32768
#define W3P_OFF (W2T_OFF + HID*HID)     // [HID][AD] float2 pairs (u,s): 98304, 4096 floats
#define B1_OFF  (W3P_OFF + HID*2*AD)    // 102400
#define B2_OFF  (B1_OFF + HID)          // 102656
#define B3P_OFF (B2_OFF + HID)          // 102912, [AD] float2 pairs
#define WS_FLOATS (B3P_OFF + 2*AD)      // 102928 floats = 411,712 bytes

__global__ __launch_bounds__(256) void prep_weights(
    const float* __restrict__ W1, const float* __restrict__ b1,
    const float* __restrict__ W2, const float* __restrict__ b2,
    const float* __restrict__ W3, const float* __restrict__ b3,
    float* __restrict__ ws) {
  int stride = gridDim.x * blockDim.x;
  for (int i = blockIdx.x * blockDim.x + threadIdx.x; i < WS_FLOATS; i += stride) {
    float v;
    if (i < W2T_OFF) {                       // W1T
      int k = i >> 8, j = i & 255;
      v = W1[j * SD + k];
    } else if (i < W3P_OFF) {                // W2T
      int t = i - W2T_OFF;
      int k = t >> 8, j = t & 255;
      v = W2[j * HID + k];
    } else if (i < B1_OFF) {                 // W3P[k][a] = (W3[a][k], W3[a+8][k])
      int t = i - W3P_OFF;
      int k = t >> 4, a = (t >> 1) & 7, h = t & 1;
      v = W3[(a + 8 * h) * HID + k];
    } else if (i < B2_OFF) {
      v = b1[i - B1_OFF];
    } else if (i < B3P_OFF) {
      v = b2[i - B2_OFF];
    } else {                                 // B3P[a] = (b3[a], b3[a+8])
      int t = i - B3P_OFF;
      v = b3[(t >> 1) + 8 * (t & 1)];
    }
    ws[i] = v;
  }
}

// R4 post-mortem: the wall is VALU instruction ISSUE. v_readlane broadcasts
// cost 32 VALU ops per 128 fmacs (25% bloat). Fix: fetch the x operand with a
// WAVE-UNIFORM address (all 64 lanes read the same 16B) — global for layer 1,
// LDS broadcast for layer 2. The value lands in a VGPR already uniform and
// feeds v_fmac v,v,v directly; the fetch rides the VMEM/LDS pipes, which have
// issue-slot headroom (VALU occupies its port 2 cyc/instr, issue port 1).

// Register/LDS-resident fused MLP. 4 waves/block, 8 rows/wave (32 rows/block).
// The [32][264] LDS buffer is reused: h1 (layer-2 broadcast source), then h2
// (layer-3 source). Wave-private rows -> NO barriers anywhere.
__global__ __launch_bounds__(256, 3) void actor_fused(
    const float* __restrict__ state, const float* __restrict__ eps,
    const float* __restrict__ ws, int* __restrict__ out) {
  __shared__ float s_h[32][264];   // 33,792 B; stride 264: 16B-aligned rows

  const int tid  = threadIdx.x;
  const int lane = tid & 63;
  const int wvu  = __builtin_amdgcn_readfirstlane(tid >> 6);  // provably uniform
  const long wrow = (long)blockIdx.x * 32 + wvu * 8;          // wave's first row

  const float4* __restrict__ W1T4 = (const float4*)(ws + W1T_OFF);  // [SD][64]
  const float4* __restrict__ W2T4 = (const float4*)(ws + W2T_OFF);  // [HID][64]
  const v2f*    __restrict__ W3P  = (const v2f*)(ws + W3P_OFF);     // [HID][8]

  const float* __restrict__ xbase = state + wrow * SD;   // uniform pointer

  // ---- layer 1: h1 = relu(x @ W1^T + b1), K = 128
  float acc[8][4];
  #pragma unroll
  for (int r = 0; r < 8; ++r)
    #pragma unroll
    for (int c = 0; c < 4; ++c) acc[r][c] = 0.0f;

  #pragma unroll 2
  for (int k0 = 0; k0 < SD; k0 += 4) {
    float4 w[4];
    #pragma unroll
    for (int j = 0; j < 4; ++j) w[j] = W1T4[(k0 + j) * 64 + lane];
    float4 xv[8];
    #pragma unroll
    for (int r = 0; r < 8; ++r)                       // uniform address: one line
      xv[r] = *(const float4*)(xbase + r * SD + k0);  // serves the whole wave
    #pragma unroll
    for (int j = 0; j < 4; ++j) {
      #pragma unroll
      for (int r = 0; r < 8; ++r) {
        float x = (j == 0) ? xv[r].x : (j == 1) ? xv[r].y
                : (j == 2) ? xv[r].z : xv[r].w;
        acc[r][0] = fmaf(x, w[j].x, acc[r][0]);
        acc[r][1] = fmaf(x, w[j].y, acc[r][1]);
        acc[r][2] = fmaf(x, w[j].z, acc[r][2]);
        acc[r][3] = fmaf(x, w[j].w, acc[r][3]);
      }
    }
  }

  // bias + relu -> wave-private LDS rows (layer-2 broadcast source; no barrier)
  {
    float4 bb = ((const float4*)(ws + B1_OFF))[lane];
    #pragma unroll
    for (int r = 0; r < 8; ++r) {
      float4 hv;
      hv.x = acc[r][0] + bb.x; hv.y = acc[r][1] + bb.y;
      hv.z = acc[r][2] + bb.z; hv.w = acc[r][3] + bb.w;
      hv.x = hv.x > 0.0f ? hv.x : 0.0f;
      hv.y = hv.y > 0.0f ? hv.y : 0.0f;
      hv.z = hv.z > 0.0f ? hv.z : 0.0f;
      hv.w = hv.w > 0.0f ? hv.w : 0.0f;
      *(float4*)&s_h[wvu * 8 + r][4 * lane] = hv;
    }
  }

  // ---- layer 2: h2 = relu(h1 @ W2^T + b2), K = 256
  #pragma unroll
  for (int r = 0; r < 8; ++r)
    #pragma unroll
    for (int c = 0; c < 4; ++c) acc[r][c] = 0.0f;

  #pragma unroll 2
  for (int k0 = 0; k0 < HID; k0 += 4) {
    float4 w[4];
    #pragma unroll
    for (int j = 0; j < 4; ++j) w[j] = W2T4[(k0 + j) * 64 + lane];
    float4 xv[8];
    #pragma unroll
    for (int r = 0; r < 8; ++r)                       // uniform LDS address ->
      xv[r] = *(const float4*)&s_h[wvu * 8 + r][k0];  // HW broadcast, conflict-free
    #pragma unroll
    for (int j = 0; j < 4; ++j) {
      #pragma unroll
      for (int r = 0; r < 8; ++r) {
        float x = (j == 0) ? xv[r].x : (j == 1) ? xv[r].y
                : (j == 2) ? xv[r].z : xv[r].w;
        acc[r][0] = fmaf(x, w[j].x, acc[r][0]);
        acc[r][1] = fmaf(x, w[j].y, acc[r][1]);
        acc[r][2] = fmaf(x, w[j].z, acc[r][2]);
        acc[r][3] = fmaf(x, w[j].w, acc[r][3]);
      }
    }
  }

  // bias + relu -> h2 into the SAME LDS rows (all h1 reads are done, program order)
  {
    float4 bb = ((const float4*)(ws + B2_OFF))[lane];
    #pragma unroll
    for (int r = 0; r < 8; ++r) {
      float4 hv;
      hv.x = acc[r][0] + bb.x; hv.y = acc[r][1] + bb.y;
      hv.z = acc[r][2] + bb.z; hv.w = acc[r][3] + bb.w;
      hv.x = hv.x > 0.0f ? hv.x : 0.0f;
      hv.y = hv.y > 0.0f ? hv.y : 0.0f;
      hv.z = hv.z > 0.0f ? hv.z : 0.0f;
      hv.w = hv.w > 0.0f ? hv.w : 0.0f;
      *(float4*)&s_h[wvu * 8 + r][4 * lane] = hv;
    }
  }

  // ---- layer 3 (K=256, N=16) + epilogue. Lane -> (row = lane>>3, action = lane&7),
  // both u and s chains serial k-ascending (matches sgemm).
  {
    const int r3 = lane >> 3;
    const int a  = lane & 7;
    const float* __restrict__ h2row = &s_h[wvu * 8 + r3][0];
    float accu = 0.0f, accs = 0.0f;
    #pragma unroll 2
    for (int k0 = 0; k0 < HID; k0 += 4) {
      v2f ha = *(const v2f*)(h2row + k0);         // 8-lane broadcast reads
      v2f hb = *(const v2f*)(h2row + k0 + 2);
      v2f wp0 = W3P[(k0 + 0) * 8 + a];
      v2f wp1 = W3P[(k0 + 1) * 8 + a];
      v2f wp2 = W3P[(k0 + 2) * 8 + a];
      v2f wp3 = W3P[(k0 + 3) * 8 + a];
      accu = fmaf(ha.x, wp0.x, accu); accs = fmaf(ha.x, wp0.y, accs);
      accu = fmaf(ha.y, wp1.x, accu); accs = fmaf(ha.y, wp1.y, accs);
      accu = fmaf(hb.x, wp2.x, accu); accs = fmaf(hb.x, wp2.y, accs);
      accu = fmaf(hb.y, wp3.x, accu); accs = fmaf(hb.y, wp3.y, accs);
    }
    v2f b3p = ((const v2f*)(ws + B3P_OFF))[a];
    float nu = accu + b3p.x;
    float ns = accs + b3p.y;

    long grow = wrow + r3;
    float sa = fabsf(ns);
    float ev = eps[grow * AD + a];                // coalesced: base + lane
    float t  = __fmul_rn(sa, ev);                 // separately-rounded mul
    float z  = __fadd_rn(nu, t);                  // separately-rounded add
    float e  = (float)exp(-(double)z);            // correctly-rounded expf near boundary
    float d  = __fadd_rn(1.0f, e);
    float act = 1.0f / d;
    float q  = act * 8.0f;                        // exact
    float wq = __fadd_rn(q, 1.0f);
    out[grow * AD + a] = (int)wq;                 // truncation, as astype(int32)
  }
}

extern "C" void kernel_launch(void* const* d_in, const int* in_sizes, int n_in,
                              void* d_out, int out_size, void* d_ws, size_t ws_size,
                              hipStream_t stream) {
  const float* state = (const float*)d_in[0];
  const float* W1    = (const float*)d_in[1];
  const float* b1    = (const float*)d_in[2];
  const float* W2    = (const float*)d_in[3];
  const float* b2    = (const float*)d_in[4];
  const float* W3    = (const float*)d_in[5];
  const float* b3    = (const float*)d_in[6];
  const float* eps   = (const float*)d_in[7];
  int*   out = (int*)d_out;
  float* ws  = (float*)d_ws;   // 411,712 bytes; rebuilt every launch

  hipLaunchKernelGGL(prep_weights, dim3(128), dim3(256), 0, stream,
                     W1, b1, W2, b2, W3, b3, ws);
  hipLaunchKernelGGL(actor_fused, dim3(NB / 32), dim3(256), 0, stream,
                     state, eps, ws, out);
}